// Round 10
// baseline (129.196 us; speedup 1.0000x reference)
//
#include <hip/hip_runtime.h>
#include <hip/hip_bf16.h>

#define HH 1024
#define LL 512
#define TNT 8              // 512/64 row-tiles
#define NTILE 36           // TNT*(TNT+1)/2 triangular 64x64 tiles

typedef __attribute__((ext_vector_type(8))) short bf16x8;
typedef __attribute__((ext_vector_type(4))) float f32x4;
typedef __attribute__((ext_vector_type(2))) float f32x2;

static constexpr float C_EXP = 2.8853900817779268f; // 2*log2(e)

// pack 8 fp32 -> 8 bf16 (RNE) as uint4
static __device__ __forceinline__ uint4 pack8(f32x4 a, f32x4 b) {
    union { uint4 u; __hip_bfloat162 h[4]; } r;
    r.h[0] = __float22bfloat162_rn(make_float2(a.x, a.y));
    r.h[1] = __float22bfloat162_rn(make_float2(a.z, a.w));
    r.h[2] = __float22bfloat162_rn(make_float2(b.x, b.y));
    r.h[3] = __float22bfloat162_rn(make_float2(b.z, b.w));
    return r.u;
}

static __device__ __forceinline__ f32x2 lo2(f32x4 v) { return __builtin_shufflevector(v, v, 0, 1); }
static __device__ __forceinline__ f32x2 hi2(f32x4 v) { return __builtin_shufflevector(v, v, 2, 3); }

// ---------------------------------------------------------------------------
// Kernel 1: bf16 MFMA projection v2 — 32m x 32n tiles, grid 1024 (4 blocks/CU
// vs previous 2: grid was the occupancy limit), register-prefetch pipeline:
// LOAD(next) issues right after STORE(cur) so HBM latency flies under
// COMPUTE(cur)+barriers. Staging set is tiny (8 float4 + 4 acc VGPR) -> no
// r7-style spill. 4 waves = 2x2 (m,n) quadrants of 16x16.
// ---------------------------------------------------------------------------
__global__ __launch_bounds__(256, 4) void proj_mfma_kernel(
    const float* __restrict__ lm, const float* __restrict__ W1,
    const float* __restrict__ b1, float* __restrict__ Ea, float* __restrict__ Eb)
{
    __shared__ ushort As[32][136];  // 136 us = 68 dw = 4 mod 32 banks: balanced
    __shared__ ushort Bs[32][136];

    const int tid  = threadIdx.x;
    const int lane = tid & 63;
    const int w    = tid >> 6;
    const int b    = blockIdx.x;          // 0..1023
    const int xcd  = b & 7;
    const int idx  = b >> 3;              // 0..127
    const int nbase = (xcd * 8 + (idx & 7)) * 32;   // 0..2047 (64 n-tiles)
    const int mbase = (idx >> 3) * 32;              // 0..480  (16 m-tiles)
    const int wm   = (w & 1) * 16;        // wave quadrant: m-offset
    const int wn   = (w >> 1) * 16;       //                n-offset
    const int sel  = nbase >> 10;         // block-uniform: Wa(0)/Wb(1)
    const int nrow = nbase & 1023;

    const int frow = lane & 15;
    const int q8   = (lane >> 4) * 8;

    // staging: thread handles rows r0a, r0a+16 of A and B at col c8
    const int r0a = tid >> 4;             // 0..15
    const int c8  = (tid & 15) * 8;

    f32x4 acc = {};
    f32x4 ld[4][2];                       // [A0,A1,B0,B1][lo,hi] = 32 VGPR

#define PLOAD(kb)                                                              \
    {                                                                          \
        const float* pa0 = &lm[(mbase + r0a) * HH + (kb) + c8];                \
        const float* pa1 = &lm[(mbase + r0a + 16) * HH + (kb) + c8];           \
        const float* pb0 = &W1[(nrow + r0a) * 2048 + sel * 1024 + (kb) + c8];  \
        const float* pb1 = &W1[(nrow + r0a + 16) * 2048 + sel * 1024 + (kb) + c8]; \
        ld[0][0] = *(const f32x4*)pa0; ld[0][1] = *(const f32x4*)(pa0 + 4);    \
        ld[1][0] = *(const f32x4*)pa1; ld[1][1] = *(const f32x4*)(pa1 + 4);    \
        ld[2][0] = *(const f32x4*)pb0; ld[2][1] = *(const f32x4*)(pb0 + 4);    \
        ld[3][0] = *(const f32x4*)pb1; ld[3][1] = *(const f32x4*)(pb1 + 4);    \
    }

#define PSTORE()                                                               \
    {                                                                          \
        *(uint4*)&As[r0a][c8]      = pack8(ld[0][0], ld[0][1]);                \
        *(uint4*)&As[r0a + 16][c8] = pack8(ld[1][0], ld[1][1]);                \
        *(uint4*)&Bs[r0a][c8]      = pack8(ld[2][0], ld[2][1]);                \
        *(uint4*)&Bs[r0a + 16][c8] = pack8(ld[3][0], ld[3][1]);                \
    }

    PLOAD(0)
    for (int kb = 0; kb < HH; kb += 128) {
        __syncthreads();                  // prev COMPUTE done -> LDS reusable
        PSTORE()                          // waits on loads(cur), cvt, ds_write
        if (kb + 128 < HH) PLOAD(kb + 128)   // prefetch flies under compute
        __syncthreads();                  // staged tile visible

#pragma unroll
        for (int s = 0; s < 4; ++s) {
            const bf16x8 a  = *(const bf16x8*)&As[wm + frow][s * 32 + q8];
            const bf16x8 bb = *(const bf16x8*)&Bs[wn + frow][s * 32 + q8];
            acc = __builtin_amdgcn_mfma_f32_16x16x32_bf16(a, bb, acc, 0, 0, 0);
        }
    }
#undef PSTORE
#undef PLOAD

    // D mapping: col=lane&15 (n), row=(lane>>4)*4+reg (m)
    const int col = lane & 15;
    const int rq  = (lane >> 4) * 4;
    const int m0  = mbase + wm + rq;
    const int nn  = nrow + wn + col;
    if (sel == 0) {
        const float bb = b1[nn];
#pragma unroll
        for (int r = 0; r < 4; ++r)
            Ea[(m0 + r) * HH + nn] = __builtin_amdgcn_exp2f(C_EXP * (acc[r] + bb));
    } else {
#pragma unroll
        for (int r = 0; r < 4; ++r)
            Eb[(m0 + r) * HH + nn] = __builtin_amdgcn_exp2f(C_EXP * acc[r]);
    }
}

// ---------------------------------------------------------------------------
// Kernel 2: triangular pairwise contraction — r3 form VERBATIM (the only
// variant measured below the 46.6us fill line; swizzles BOTH j-side and
// i-side LDS reads, fixing the 4-way bank conflict the 32x32 shells carry).
// ---------------------------------------------------------------------------
__global__ __launch_bounds__(256, 3) void pair_kernel(
    const float* __restrict__ Ea, const float* __restrict__ Eb,
    const float* __restrict__ W2, float* __restrict__ pbuf, int slice)
{
    __shared__ float tl[4][64][32];   // [0]=Ea[j] [1]=Eb[j] [2]=Ea[i] [3]=Eb[i]

    const int tid = threadIdx.x;
    const int tx  = tid & 15;
    const int ty  = tid >> 4;         // 0..15

    int tt = blockIdx.x, bi = 0, rem = TNT;          // triangular decode
    while (tt >= rem) { tt -= rem; --rem; ++bi; }
    const int bj    = bi + tt;
    const int ibase = bi * 64;
    const int jbase = bj * 64;
    const int k0    = blockIdx.y * slice;

    f32x2 acc0[4][4] = {};   // [ii][jj], h-packed partial sums, channel 0
    f32x2 acc1[4][4] = {};   // channel 1
    const f32x2 one2 = {1.f, 1.f};

    for (int kb = 0; kb < slice; kb += 32) {
        if (kb) __syncthreads();
        {   // stage 4 tiles x 64 rows x 32 floats = 2048 float4, 8/thread
            const int c4  = tid & 7;
            const int r0  = tid >> 3;                // 0..31
            const int hof = k0 + kb + c4 * 4;
#pragma unroll
            for (int it = 0; it < 8; ++it) {
                const int tile = it >> 1;            // compile-time per it
                const int row  = (it & 1) * 32 + r0;
                const int base = (tile < 2) ? jbase : ibase;
                const float* src = (tile == 0 || tile == 2) ? Ea : Eb;
                const int c4s = c4 ^ (row & 7);
                *(f32x4*)&tl[tile][row][c4s * 4] =
                    *(const f32x4*)&src[(size_t)(base + row) * HH + hof];
            }
        }
        __syncthreads();

#pragma unroll 2
        for (int h4 = 0; h4 < 8; ++h4) {
            const int sxj = (h4 ^ (tx & 7)) * 4;     // xor-swizzled float4 slot
            const int sxi = (h4 ^ (ty & 7)) * 4;

            // hoisted i-side (broadcast reads), split into pk-ready halves
            f32x2 ailo[4], aihi[4], bilo[4], bihi[4];
#pragma unroll
            for (int ii = 0; ii < 4; ++ii) {
                const f32x4 Ai = *(const f32x4*)&tl[2][ty + 16 * ii][sxi];
                const f32x4 Bi = *(const f32x4*)&tl[3][ty + 16 * ii][sxi];
                ailo[ii] = lo2(Ai); aihi[ii] = hi2(Ai);
                bilo[ii] = lo2(Bi); bihi[ii] = hi2(Bi);
            }
            const f32x4 w0q = *(const f32x4*)&W2[k0 + kb + h4 * 4];      // uniform
            const f32x4 w1q = *(const f32x4*)&W2[HH + k0 + kb + h4 * 4];
            const f32x2 w0lo = lo2(w0q), w0hi = hi2(w0q);
            const f32x2 w1lo = lo2(w1q), w1hi = hi2(w1q);

#pragma unroll
            for (int jj = 0; jj < 4; ++jj) {
                const f32x4 Aj = *(const f32x4*)&tl[0][tx + 16 * jj][sxj];
                const f32x4 Bj = *(const f32x4*)&tl[1][tx + 16 * jj][sxj];
                const f32x2 ajlo = lo2(Aj), ajhi = hi2(Aj);
                const f32x2 bjlo = lo2(Bj), bjhi = hi2(Bj);
#pragma unroll
                for (int ii = 0; ii < 4; ++ii) {
                    // d = 1 + Eb_i*Ea_j ; e = 1 + Ea_i*Eb_j   (h-packed pairs)
                    const f32x2 d01 = __builtin_elementwise_fma(bilo[ii], ajlo, one2);
                    const f32x2 d23 = __builtin_elementwise_fma(bihi[ii], ajhi, one2);
                    const f32x2 e01 = __builtin_elementwise_fma(ailo[ii], bjlo, one2);
                    const f32x2 e23 = __builtin_elementwise_fma(aihi[ii], bjhi, one2);
                    // 1/d + 1/e = (d+e)/(d*e); batch-rcp the 4 products (>=1)
                    const f32x2 n01 = d01 + e01, n23 = d23 + e23;
                    const f32x2 m01 = d01 * e01, m23 = d23 * e23;
                    const float p01 = m01.x * m01.y;
                    const float p23 = m23.x * m23.y;
                    const float R   = __builtin_amdgcn_rcpf(p01 * p23);
                    const float r01 = R * p23;       // = 1/p01
                    const float r23 = R * p01;       // = 1/p23
                    const f32x2 u01 = (n01 * __builtin_shufflevector(m01, m01, 1, 0))
                                      * (f32x2){r01, r01};
                    const f32x2 u23 = (n23 * __builtin_shufflevector(m23, m23, 1, 0))
                                      * (f32x2){r23, r23};
                    acc0[ii][jj] = __builtin_elementwise_fma(u01, w0lo, acc0[ii][jj]);
                    acc0[ii][jj] = __builtin_elementwise_fma(u23, w0hi, acc0[ii][jj]);
                    acc1[ii][jj] = __builtin_elementwise_fma(u01, w1lo, acc1[ii][jj]);
                    acc1[ii][jj] = __builtin_elementwise_fma(u23, w1hi, acc1[ii][jj]);
                }
            }
        }
    }

    float* pb = pbuf + ((size_t)blockIdx.y * NTILE + blockIdx.x) * 8192;
#pragma unroll
    for (int ii = 0; ii < 4; ++ii)
#pragma unroll
        for (int jj = 0; jj < 4; ++jj) {
            const int li = ty + 16 * ii, lj = tx + 16 * jj;
            const f32x2 v = { acc0[ii][jj].x + acc0[ii][jj].y,
                              acc1[ii][jj].x + acc1[ii][jj].y };
            *(f32x2*)&pb[(li * 64 + lj) * 2] = v;
        }
}

// ---------------------------------------------------------------------------
// Kernel 3: combine (r3 form, passed): out = wsum[c]+b2[c] - sum_z pbuf.
// ---------------------------------------------------------------------------
__global__ __launch_bounds__(256) void combine_kernel(
    const float* __restrict__ pbuf, const float* __restrict__ W2,
    const float* __restrict__ b2, float* __restrict__ out, int nz)
{
    __shared__ float s_ws[2];

    const int tid = threadIdx.x;
    if (tid < 128) {
        const int c = tid >> 6, l = tid & 63;
        float s = 0.f;
#pragma unroll
        for (int q = 0; q < 4; ++q) {
            const f32x4 v = *(const f32x4*)&W2[c * HH + (l + q * 64) * 4];
            s += v.x + v.y + v.z + v.w;
        }
#pragma unroll
        for (int off = 32; off; off >>= 1) s += __shfl_down(s, off, 64);
        if (l == 0) s_ws[c] = s + b2[c];
    }
    __syncthreads();

    const int idx   = blockIdx.x * 256 + tid;   // 0 .. 36*8192-1
    const int t     = idx >> 13;                // block-uniform (8192/256=32)
    const int local = idx & 8191;
    int tt = t, bi = 0, rem = TNT;
    while (tt >= rem) { tt -= rem; --rem; ++bi; }
    const int bj = bi + tt;

    float s0 = 0.f, s1 = 0.f, s2 = 0.f, s3 = 0.f;
    for (int z = 0; z < nz; z += 4) {   // nz in {8,16,32}
        s0 += pbuf[((size_t)z * NTILE + t) * 8192 + local];
        s1 += pbuf[((size_t)(z + 1) * NTILE + t) * 8192 + local];
        s2 += pbuf[((size_t)(z + 2) * NTILE + t) * 8192 + local];
        s3 += pbuf[((size_t)(z + 3) * NTILE + t) * 8192 + local];
    }
    const float s = (s0 + s1) + (s2 + s3);

    const int li = local >> 7;          // 0..63
    const int lj = (local >> 1) & 63;
    const int c  = local & 1;
    const float v = s_ws[c] - s;

    const int i = bi * 64 + li;
    const int j = bj * 64 + lj;
    out[(i * LL + j) * 2 + c] = v;
    out[(j * LL + i) * 2 + c] = v;   // diagonal tiles: same-value rewrite, benign
}

extern "C" void kernel_launch(void* const* d_in, const int* in_sizes, int n_in,
                              void* d_out, int out_size, void* d_ws, size_t ws_size,
                              hipStream_t stream)
{
    const float* lm = (const float*)d_in[0];
    const float* W1 = (const float*)d_in[1];
    const float* b1 = (const float*)d_in[2];
    const float* W2 = (const float*)d_in[3];
    const float* b2 = (const float*)d_in[4];
    float* out = (float*)d_out;

    char* ws = (char*)d_ws;
    float* Ea   = (float*)ws;                            // 2 MB
    float* Eb   = (float*)(ws + (2u << 20));             // 2 MB
    float* pbuf = (float*)(ws + (4u << 20) + 64);        // nz * 1.18 MB

    const size_t ubase = (4u << 20) + 64;
    const size_t per_z = (size_t)NTILE * 8192 * 4;       // 1.18 MB per z-slice
    int nz = 8;                                          // 288 blocks (safe floor)
    if      (ws_size >= ubase + 32 * per_z) nz = 32;     // 1152 blocks, 4.5/CU
    else if (ws_size >= ubase + 16 * per_z) nz = 16;     // 576 blocks
    const int slice = HH / nz;

    proj_mfma_kernel<<<1024, 256, 0, stream>>>(lm, W1, b1, Ea, Eb);
    pair_kernel<<<dim3(NTILE, nz), 256, 0, stream>>>(Ea, Eb, W2, pbuf, slice);
    combine_kernel<<<(NTILE * 8192) / 256, 256, 0, stream>>>(pbuf, W2, b2, out, nz);
}

// Round 11
// 128.400 us; speedup vs baseline: 1.0062x; 1.0062x over previous
//
#include <hip/hip_runtime.h>
#include <hip/hip_bf16.h>

#define HH 1024
#define LL 512
#define NT 16              // 512/32 row-tiles
#define NTRI 136           // NT*(NT+1)/2 triangular tiles
#define NZ 16              // z-slices: slice = 64 -> 2 kb-iters of 32

typedef __attribute__((ext_vector_type(8))) short bf16x8;
typedef __attribute__((ext_vector_type(4))) float f32x4;
typedef __attribute__((ext_vector_type(2))) float f32x2;

static constexpr float C_EXP = 2.8853900817779268f; // 2*log2(e)

// pack 8 fp32 -> 8 bf16 (RNE) as uint4
static __device__ __forceinline__ uint4 pack8(f32x4 a, f32x4 b) {
    union { uint4 u; __hip_bfloat162 h[4]; } r;
    r.h[0] = __float22bfloat162_rn(make_float2(a.x, a.y));
    r.h[1] = __float22bfloat162_rn(make_float2(a.z, a.w));
    r.h[2] = __float22bfloat162_rn(make_float2(b.x, b.y));
    r.h[3] = __float22bfloat162_rn(make_float2(b.z, b.w));
    return r.u;
}

// ---------------------------------------------------------------------------
// Kernel 1: bf16 MFMA projection — 32m x 32n, grid 1024, kb-step 64 so LDS
// drops 17.4 -> 9.2 KB (occupancy is gated by an effective ~64-76 KB/CU LDS
// budget, per the session's occupancy-counter correlation). Register
// prefetch pipeline retained (16 VGPR staging set).
// ---------------------------------------------------------------------------
__global__ __launch_bounds__(256, 8) void proj_mfma_kernel(
    const float* __restrict__ lm, const float* __restrict__ W1,
    const float* __restrict__ b1, float* __restrict__ Ea, float* __restrict__ Eb)
{
    __shared__ ushort As[32][72];   // 72 us = 36 dw = 4 mod 32 banks
    __shared__ ushort Bs[32][72];   // total 9216 B

    const int tid  = threadIdx.x;
    const int lane = tid & 63;
    const int w    = tid >> 6;
    const int b    = blockIdx.x;          // 0..1023
    const int xcd  = b & 7;
    const int idx  = b >> 3;              // 0..127
    const int nbase = (xcd * 8 + (idx & 7)) * 32;   // 0..2047 (64 n-tiles)
    const int mbase = (idx >> 3) * 32;              // 0..480  (16 m-tiles)
    const int wm   = (w & 1) * 16;        // wave quadrant: m-offset
    const int wn   = (w >> 1) * 16;       //                n-offset
    const int sel  = nbase >> 10;         // block-uniform: Wa(0)/Wb(1)
    const int nrow = nbase & 1023;

    const int frow = lane & 15;
    const int q8   = (lane >> 4) * 8;

    // staging: thread handles (row r0a, 8 cols at c8) of A and of B
    const int r0a = tid >> 3;             // 0..31
    const int c8  = (tid & 7) * 8;        // 0..56

    f32x4 acc = {};
    f32x4 ld[2][2];                       // [A,B][lo,hi] = 16 VGPR

#define PLOAD(kb)                                                              \
    {                                                                          \
        const float* pa = &lm[(mbase + r0a) * HH + (kb) + c8];                 \
        const float* pw = &W1[(nrow + r0a) * 2048 + sel * 1024 + (kb) + c8];   \
        ld[0][0] = *(const f32x4*)pa; ld[0][1] = *(const f32x4*)(pa + 4);      \
        ld[1][0] = *(const f32x4*)pw; ld[1][1] = *(const f32x4*)(pw + 4);      \
    }

#define PSTORE()                                                               \
    {                                                                          \
        *(uint4*)&As[r0a][c8] = pack8(ld[0][0], ld[0][1]);                     \
        *(uint4*)&Bs[r0a][c8] = pack8(ld[1][0], ld[1][1]);                     \
    }

    PLOAD(0)
    for (int kb = 0; kb < HH; kb += 64) {
        __syncthreads();                  // prev compute done -> LDS reusable
        PSTORE()
        if (kb + 64 < HH) PLOAD(kb + 64)  // prefetch flies under compute
        __syncthreads();                  // staged tile visible

#pragma unroll
        for (int s = 0; s < 2; ++s) {
            const bf16x8 a  = *(const bf16x8*)&As[wm + frow][s * 32 + q8];
            const bf16x8 bb = *(const bf16x8*)&Bs[wn + frow][s * 32 + q8];
            acc = __builtin_amdgcn_mfma_f32_16x16x32_bf16(a, bb, acc, 0, 0, 0);
        }
    }
#undef PSTORE
#undef PLOAD

    // D mapping: col=lane&15 (n), row=(lane>>4)*4+reg (m)
    const int col = lane & 15;
    const int rq  = (lane >> 4) * 4;
    const int m0  = mbase + wm + rq;
    const int nn  = nrow + wn + col;
    if (sel == 0) {
        const float bb = b1[nn];
#pragma unroll
        for (int r = 0; r < 4; ++r)
            Ea[(m0 + r) * HH + nn] = __builtin_amdgcn_exp2f(C_EXP * (acc[r] + bb));
    } else {
#pragma unroll
        for (int r = 0; r < 4; ++r)
            Eb[(m0 + r) * HH + nn] = __builtin_amdgcn_exp2f(C_EXP * acc[r]);
    }
}

// ---------------------------------------------------------------------------
// Kernel 2: triangular pairwise contraction — r0 shell + VERBATIM r0 math
// (best measured), ONE change: LDS 32 -> 16 KB ([4][32][32], kb-step 32) to
// double residency under the effective ~64-76 KB/CU LDS occupancy budget
// (32 KB variants all measured 23-30% occupancy; the 16 KB variant 44-47%).
// Both-side XOR swizzle (&7) keeps all reads <=2-way.
// ---------------------------------------------------------------------------
__global__ __launch_bounds__(256, 6) void pair_kernel(
    const float* __restrict__ Ea, const float* __restrict__ Eb,
    const float* __restrict__ W2, float* __restrict__ pbuf, int slice)
{
    // [0]=Ea[j] [1]=Ea[i] [2]=Eb[i] [3]=Eb[j] ; 16384 B total
    __shared__ float tl[4][32][32];

    const int tid = threadIdx.x;
    const int tx  = tid & 15;
    const int ty  = tid >> 4;         // 0..15

    int tt = blockIdx.x, bi = 0, rem = NT;          // triangular decode
    while (tt >= rem) { tt -= rem; --rem; ++bi; }
    const int bj    = bi + tt;
    const int ibase = bi * 32;
    const int jbase = bj * 32;
    const int k0    = blockIdx.y * slice;

    f32x2 aC0[2] = {}, aC1[2] = {};   // [ii], packed over jj
    const f32x2 one2 = {1.f, 1.f};

    for (int kb = 0; kb < slice; kb += 32) {
        if (kb) __syncthreads();
        {   // stage 4 tiles x 32 rows x 32 floats = 1024 float4, 4/thread
            const int row = tid >> 3;            // 0..31
            const int c4  = tid & 7;             // 0..7
            const int c4s = c4 ^ (row & 7);      // XOR involution, all tiles
            const int hof = k0 + kb + c4 * 4;
            *(f32x4*)&tl[0][row][c4s * 4] = *(const f32x4*)&Ea[(jbase + row) * HH + hof];
            *(f32x4*)&tl[1][row][c4s * 4] = *(const f32x4*)&Ea[(ibase + row) * HH + hof];
            *(f32x4*)&tl[2][row][c4s * 4] = *(const f32x4*)&Eb[(ibase + row) * HH + hof];
            *(f32x4*)&tl[3][row][c4s * 4] = *(const f32x4*)&Eb[(jbase + row) * HH + hof];
        }
        __syncthreads();

#pragma unroll 4
        for (int h4 = 0; h4 < 8; ++h4) {
            const int sx  = (h4 ^ (tx & 7)) * 4;   // read-side swizzle (j rows)
            const int sxi = (h4 ^ (ty & 7)) * 4;   // read-side swizzle (i rows)
            const f32x4 Aj0 = *(const f32x4*)&tl[0][tx][sx];
            const f32x4 Aj1 = *(const f32x4*)&tl[0][tx + 16][sx];
            const f32x4 Bj0 = *(const f32x4*)&tl[3][tx][sx];
            const f32x4 Bj1 = *(const f32x4*)&tl[3][tx + 16][sx];
            const f32x4 Ai0 = *(const f32x4*)&tl[1][ty][sxi];
            const f32x4 Ai1 = *(const f32x4*)&tl[1][ty + 16][sxi];
            const f32x4 Bi0 = *(const f32x4*)&tl[2][ty][sxi];
            const f32x4 Bi1 = *(const f32x4*)&tl[2][ty + 16][sxi];
            const f32x4 w0q = *(const f32x4*)&W2[k0 + kb + h4 * 4];      // uniform
            const f32x4 w1q = *(const f32x4*)&W2[HH + k0 + kb + h4 * 4];

#define DO_H(AJ0v, AJ1v, BI0v, BI1v, AI0v, AI1v, BJ0v, BJ1v, W0s, W1s)        \
            {                                                                  \
                const f32x2 Aj = {AJ0v, AJ1v};                                 \
                const f32x2 Bj = {BJ0v, BJ1v};                                 \
                const f32x2 d0 = __builtin_elementwise_fma((f32x2){BI0v, BI0v}, Aj, one2); \
                const f32x2 d1 = __builtin_elementwise_fma((f32x2){BI1v, BI1v}, Aj, one2); \
                const f32x2 e0 = __builtin_elementwise_fma((f32x2){AI0v, AI0v}, Bj, one2); \
                const f32x2 e1 = __builtin_elementwise_fma((f32x2){AI1v, AI1v}, Bj, one2); \
                const float dp0 = d0.x * d0.y, dp1 = d1.x * d1.y;              \
                const float ep0 = e0.x * e0.y, ep1 = e1.x * e1.y;              \
                const float DR = __builtin_amdgcn_rcpf(dp0 * dp1);             \
                const float ER = __builtin_amdgcn_rcpf(ep0 * ep1);             \
                const f32x2 dq = (f32x2){DR, DR} * (f32x2){dp1, dp0};          \
                const f32x2 eq = (f32x2){ER, ER} * (f32x2){ep1, ep0};          \
                const f32x2 u0 = (f32x2){dq.x, dq.x} * __builtin_shufflevector(d0, d0, 1, 0) \
                               + (f32x2){eq.x, eq.x} * __builtin_shufflevector(e0, e0, 1, 0); \
                const f32x2 u1 = (f32x2){dq.y, dq.y} * __builtin_shufflevector(d1, d1, 1, 0) \
                               + (f32x2){eq.y, eq.y} * __builtin_shufflevector(e1, e1, 1, 0); \
                aC0[0] = __builtin_elementwise_fma(u0, (f32x2){(W0s), (W0s)}, aC0[0]); \
                aC1[0] = __builtin_elementwise_fma(u0, (f32x2){(W1s), (W1s)}, aC1[0]); \
                aC0[1] = __builtin_elementwise_fma(u1, (f32x2){(W0s), (W0s)}, aC0[1]); \
                aC1[1] = __builtin_elementwise_fma(u1, (f32x2){(W1s), (W1s)}, aC1[1]); \
            }
            DO_H(Aj0.x, Aj1.x, Bi0.x, Bi1.x, Ai0.x, Ai1.x, Bj0.x, Bj1.x, w0q.x, w1q.x)
            DO_H(Aj0.y, Aj1.y, Bi0.y, Bi1.y, Ai0.y, Ai1.y, Bj0.y, Bj1.y, w0q.y, w1q.y)
            DO_H(Aj0.z, Aj1.z, Bi0.z, Bi1.z, Ai0.z, Ai1.z, Bj0.z, Bj1.z, w0q.z, w1q.z)
            DO_H(Aj0.w, Aj1.w, Bi0.w, Bi1.w, Ai0.w, Ai1.w, Bj0.w, Bj1.w, w0q.w, w1q.w)
#undef DO_H
        }
    }

    // u0/u1 are jj-packed: value(ii,jj,c) = (c ? aC1 : aC0)[ii][jj]
    float* pb = pbuf + ((size_t)blockIdx.y * NTRI + blockIdx.x) * 2048;
#pragma unroll
    for (int ii = 0; ii < 2; ++ii)
#pragma unroll
        for (int jj = 0; jj < 2; ++jj) {
            const int li = ty + ii * 16, lj = tx + jj * 16;
            const f32x2 v = { jj ? aC0[ii].y : aC0[ii].x,
                              jj ? aC1[ii].y : aC1[ii].x };
            *(f32x2*)&pb[(li * 32 + lj) * 2] = v;
        }
}

// ---------------------------------------------------------------------------
// Kernel 3: combine (r0 proven form): out = wsum[c]+b2[c] - sum_z pbuf;
// scatter to (i,j) and (j,i). 1088 blocks, 2-way ILP on z.
// ---------------------------------------------------------------------------
__global__ __launch_bounds__(256) void combine_kernel(
    const float* __restrict__ pbuf, const float* __restrict__ W2,
    const float* __restrict__ b2, float* __restrict__ out, int nz)
{
    __shared__ float s_ws[2];

    const int tid = threadIdx.x;
    if (tid < 128) {
        const int c = tid >> 6, l = tid & 63;
        float s = 0.f;
#pragma unroll
        for (int q = 0; q < 4; ++q) {
            const f32x4 v = *(const f32x4*)&W2[c * HH + (l + q * 64) * 4];
            s += v.x + v.y + v.z + v.w;
        }
#pragma unroll
        for (int off = 32; off; off >>= 1) s += __shfl_down(s, off, 64);
        if (l == 0) s_ws[c] = s + b2[c];
    }
    __syncthreads();

    const int idx   = blockIdx.x * 256 + tid;   // 0 .. 136*2048-1
    const int t     = idx >> 11;                // block-uniform
    const int local = idx & 2047;
    int tt = t, bi = 0, rem = NT;
    while (tt >= rem) { tt -= rem; --rem; ++bi; }
    const int bj = bi + tt;

    float s0 = 0.f, s1 = 0.f;
    for (int z = 0; z < nz; z += 2) {   // nz is even
        s0 += pbuf[((size_t)z * NTRI + t) * 2048 + local];
        s1 += pbuf[((size_t)(z + 1) * NTRI + t) * 2048 + local];
    }
    const float s = s0 + s1;

    const int li = local >> 6;
    const int lj = (local >> 1) & 31;
    const int c  = local & 1;
    const float v = s_ws[c] - s;

    const int i = bi * 32 + li;
    const int j = bj * 32 + lj;
    out[(i * LL + j) * 2 + c] = v;
    out[(j * LL + i) * 2 + c] = v;   // diagonal tiles: same-value rewrite, benign
}

extern "C" void kernel_launch(void* const* d_in, const int* in_sizes, int n_in,
                              void* d_out, int out_size, void* d_ws, size_t ws_size,
                              hipStream_t stream)
{
    const float* lm = (const float*)d_in[0];
    const float* W1 = (const float*)d_in[1];
    const float* b1 = (const float*)d_in[2];
    const float* W2 = (const float*)d_in[3];
    const float* b2 = (const float*)d_in[4];
    float* out = (float*)d_out;

    char* ws = (char*)d_ws;
    float* Ea   = (float*)ws;                            // 2 MB
    float* Eb   = (float*)(ws + (2u << 20));             // 2 MB
    float* pbuf = (float*)(ws + (4u << 20) + 64);        // 16 * 1.11 MB = 17.8 MB

    const int nz = NZ;                 // 16 (session ws = 256 MB, proven by fills)
    const int slice = HH / nz;         // 64 -> 2 kb-iters of 32 per pair block

    proj_mfma_kernel<<<1024, 256, 0, stream>>>(lm, W1, b1, Ea, Eb);
    pair_kernel<<<dim3(NTRI, nz), 256, 0, stream>>>(Ea, Eb, W2, pbuf, slice);
    combine_kernel<<<(NTRI * 2048) / 256, 256, 0, stream>>>(pbuf, W2, b2, out, nz);
}